// Round 10
// baseline (519.509 us; speedup 1.0000x reference)
//
#include <hip/hip_runtime.h>
#include <hip/hip_bf16.h>

// Problem dims
constexpr int kS = 512;
constexpr int kB = 64;
constexpr int kE = 300;
constexpr int kH = 256;
constexpr int kM = 512;
constexpr int kC = 20;

typedef short s16x8 __attribute__((ext_vector_type(8)));
typedef float f32x4 __attribute__((ext_vector_type(4)));
typedef unsigned short u16x4 __attribute__((ext_vector_type(4)));
typedef _Float16 f16x8 __attribute__((ext_vector_type(8)));
typedef __fp16 hf16x2 __attribute__((ext_vector_type(2)));

__device__ __forceinline__ float fast_tanh(float z) {
    z = fminf(15.f, fmaxf(-15.f, z));
    float e = __expf(2.f * z);
    return 1.f - 2.f / (e + 1.f);
}

__device__ __forceinline__ unsigned short f2bf(float f) {
    __hip_bfloat16 h = __float2bfloat16(f);
    return *(unsigned short*)&h;
}
union F16U { _Float16 h; unsigned short u; };
__device__ __forceinline__ unsigned short f16bits(_Float16 h) { F16U x; x.h = h; return x.u; }

// LDS-only barrier: waits ds ops, NOT global ops (no vmcnt drain). Safe in the
// scan because global traffic there is strictly thread-private (own 8B slots);
// all cross-thread exchange is via LDS. Prefetch-register consumption is
// ordered by compiler-counted vmcnt waits.
__device__ __forceinline__ void lds_barrier() {
    asm volatile("s_waitcnt lgkmcnt(0)\n\ts_barrier" ::: "memory");
}

// ---------------------------------------------------------------------------
// Buffers:
//   E   [32768][320] bf16 : emb (300) + zero pad (20); row = b*512+s
//   XCL [512][64][256] bf16: proj pre-acts -> scan overwrites with c_ls (in place)
//   XCR [512][64][256] bf16: same for right scan
//   Wmax [512][832] bf16 (re-ordered cols to match XCL|E|XCR concat)
//   Wproj [512][320] bf16, Wscan [2][256][256] f16
// ---------------------------------------------------------------------------

__global__ __launch_bounds__(256) void prepw_kernel(
    const float* __restrict__ max_w,
    const float* __restrict__ wsl, const float* __restrict__ wsr,
    const float* __restrict__ wl, const float* __restrict__ wr,
    unsigned short* __restrict__ Wmax, unsigned short* __restrict__ Wproj,
    unsigned short* __restrict__ Wscan)
{
    int idx = blockIdx.x * 256 + threadIdx.x;
    if (idx < 512 * 832) {
        int r = idx / 832, c = idx - r * 832;
        float v;
        if (c < 556)      v = max_w[r * 812 + c];
        else if (c < 576) v = 0.f;
        else              v = max_w[r * 812 + (c - 20)];
        Wmax[idx] = f2bf(v);
    }
    if (idx < 512 * 320) {
        int r = idx / 320, c = idx - r * 320;
        float v = 0.f;
        if (c < 300) v = (r < 256) ? wsl[r * 300 + c] : wsr[(r - 256) * 300 + c];
        Wproj[idx] = f2bf(v);
    }
    if (idx < 2 * 256 * 256) {
        int d = idx >> 16, rc = idx & 65535;
        float v = (d ? wr : wl)[rc];
        Wscan[idx] = f16bits((_Float16)v);
    }
}

// gather: emb rows -> E[b*512+s][0..300), zeros [300,320)
__global__ __launch_bounds__(128) void gather_kernel(
    const int* __restrict__ inp, const float* __restrict__ emb_table,
    unsigned short* __restrict__ E)
{
    const int row = blockIdx.x;          // b*512 + s
    const int b = row >> 9, s = row & 511;
    const int t = threadIdx.x;
    unsigned short* dst = E + (size_t)row * 320;
    const int v = inp[s * kB + b];
    const float* src = emb_table + (size_t)v * kE;
    if (t < 75) {
        float4 f = *(const float4*)&src[t * 4];
        u16x4 o = { f2bf(f.x), f2bf(f.y), f2bf(f.z), f2bf(f.w) };
        *(u16x4*)&dst[t * 4] = o;
    } else if (t < 80) {
        u16x4 z = { 0, 0, 0, 0 };
        *(u16x4*)&dst[300 + (t - 75) * 4] = z;
    }
}

// proj GEMM: A = E (K=320), B = Wproj. Epilogue -> XCL/XCR [s][b][256] bf16.
__global__ __launch_bounds__(256) void proj_mfma_kernel(
    const unsigned short* __restrict__ E,
    const unsigned short* __restrict__ Wproj,
    const float* __restrict__ b_sl, const float* __restrict__ b_sr,
    unsigned short* __restrict__ XCL, unsigned short* __restrict__ XCR)
{
    __shared__ unsigned short As[128 * 40];
    __shared__ unsigned short Bs[128 * 40];
    const int tid = threadIdx.x;
    const int row0 = blockIdx.x * 128;
    const int col0 = blockIdx.y * 128;
    const int lane = tid & 63;
    const int wave = tid >> 6;
    const int wr = (wave >> 1) * 64, wc = (wave & 1) * 64;
    const int l15 = lane & 15, lk = (lane >> 4) * 8;
    const int srow = tid >> 1;
    const int sh = (tid & 1) * 16;

    const unsigned short* Ag = E + (size_t)(row0 + srow) * 320 + sh;
    const unsigned short* Bg = Wproj + (size_t)(col0 + srow) * 320 + sh;

    f32x4 acc[4][4] = {};
    float4 av0 = *(const float4*)Ag;
    float4 av1 = *(const float4*)(Ag + 8);
    float4 bv0 = *(const float4*)Bg;
    float4 bv1 = *(const float4*)(Bg + 8);

    for (int kk = 0; kk < 10; ++kk) {
        __syncthreads();
        *(float4*)&As[srow * 40 + sh] = av0;
        *(float4*)&As[srow * 40 + sh + 8] = av1;
        *(float4*)&Bs[srow * 40 + sh] = bv0;
        *(float4*)&Bs[srow * 40 + sh + 8] = bv1;
        __syncthreads();
        if (kk < 9) {
            av0 = *(const float4*)(Ag + (kk + 1) * 32);
            av1 = *(const float4*)(Ag + (kk + 1) * 32 + 8);
            bv0 = *(const float4*)(Bg + (kk + 1) * 32);
            bv1 = *(const float4*)(Bg + (kk + 1) * 32 + 8);
        }
        s16x8 af[4], bf[4];
#pragma unroll
        for (int f = 0; f < 4; ++f) {
            af[f] = *(const s16x8*)&As[(wr + f * 16 + l15) * 40 + lk];
            bf[f] = *(const s16x8*)&Bs[(wc + f * 16 + l15) * 40 + lk];
        }
#pragma unroll
        for (int i = 0; i < 4; ++i)
#pragma unroll
            for (int j = 0; j < 4; ++j)
                acc[i][j] = __builtin_amdgcn_mfma_f32_16x16x32_bf16(af[i], bf[j], acc[i][j], 0, 0, 0);
    }

    const int rbase = row0 + wr + (lane >> 4) * 4;
#pragma unroll
    for (int j = 0; j < 4; ++j) {
        const int col = col0 + wc + j * 16 + l15;           // h' in [0,512)
        const float bias = (col < kH) ? b_sl[col] : b_sr[col - kH];
        unsigned short* X = (col < kH) ? XCL : XCR;
        const int ccol = col & 255;
#pragma unroll
        for (int i = 0; i < 4; ++i) {
#pragma unroll
            for (int r = 0; r < 4; ++r) {
                const int row = rbase + i * 16 + r;         // b*512+s
                const int s = row & 511, b = row >> 9;
                X[((size_t)s * 64 + b) * 256 + ccol] = f2bf(acc[i][j][r] + bias);
            }
        }
    }
}

// ---------------------------------------------------------------------------
// MFMA scan, swapped operands (A=W, B=c). 8 blocks = 2 dir x 4 bgroups of 16.
// 512 threads (8 waves); wave owns 32 output cols. C/D layout: col(lane&15)=
// batch, row(q4*4+r)=output col -> each thread owns 4 CONSECUTIVE cols of one
// batch => 8B vector global load/store and ds_write_b64, cvt_pk packing.
// Single-f16 recurrence in swizzled double-buffered LDS; 1 LDS-only barrier
// per step (global c-stores/x-loads are thread-private -> no vmcnt drain).
// ---------------------------------------------------------------------------
__global__ __launch_bounds__(512, 2) void scan_mfma_kernel(
    const float* __restrict__ c_l0, const float* __restrict__ c_r0,
    const float* __restrict__ b_l, const float* __restrict__ b_r,
    const unsigned short* __restrict__ Wscan,   // [2][256][256] f16
    unsigned short* __restrict__ XCL, unsigned short* __restrict__ XCR)
{
    __shared__ unsigned short cF[2][16 * 256];

    const int dir = blockIdx.x >> 2;
    const int bg  = blockIdx.x & 3;
    const int tid = threadIdx.x;
    const int lane = tid & 63;
    const int wave = tid >> 6;          // 0..7
    const int l15 = lane & 15;          // batch-in-group; cF row
    const int q4  = lane >> 4;          // k-slice for frags; col-subtile out
    const int n0  = wave * 32;

    const float* bias = dir ? b_r : b_l;
    const float* c0v  = dir ? c_r0 : c_l0;
    const unsigned short* W = Wscan + (dir << 16);
    unsigned short* XC = dir ? XCR : XCL;

    // A-frags (W): rows n0+j*16+l15 (output cols), k = ks*32 + q4*8
    f16x8 wf[2][8];
#pragma unroll
    for (int j = 0; j < 2; ++j)
#pragma unroll
        for (int ks = 0; ks < 8; ++ks)
            wf[j][ks] = *(const f16x8*)&W[(n0 + j * 16 + l15) * 256 + ks * 32 + q4 * 8];

    // biases for this thread's 8 output cols
    float biasv[2][4];
#pragma unroll
    for (int j = 0; j < 2; ++j)
#pragma unroll
        for (int r = 0; r < 4; ++r)
            biasv[j][r] = bias[n0 + j * 16 + q4 * 4 + r];

    // global slot (shorts): batch (bg*16+l15), cols n0+q4*4 (+j*16 imm)
    const unsigned int base0 = (unsigned)((bg * 16 + l15) * 256 + n0 + q4 * 4);

    // swizzled LDS offsets (row = l15 for both read and write)
    int ridx[8], widx[2];
#pragma unroll
    for (int ks = 0; ks < 8; ++ks)
        ridx[ks] = (l15 * 256 + ks * 32 + q4 * 8) ^ ((l15 & 7) << 3);
#pragma unroll
    for (int j = 0; j < 2; ++j)
        widx[j] = (l15 * 256 + n0 + j * 16 + q4 * 4) ^ ((l15 & 7) << 3);

    // init c0 into cF[0] (all 16 batch rows share c0)
    if (tid < 256) {
        unsigned short hb = f16bits((_Float16)c0v[tid]);
        for (int row = 0; row < 16; ++row)
            cF[0][(row * 256 + tid) ^ ((row & 7) << 3)] = hb;
    }

    // prologue x loads: steps 0,1
    const int s0i = dir ? 511 : 0;
    const int s1i = dir ? 510 : 1;
    uint2 xa[2], xb[2];
#pragma unroll
    for (int j = 0; j < 2; ++j) {
        xa[j] = *(const uint2*)(XC + base0 + (unsigned)s0i * 16384u + j * 16);
        xb[j] = *(const uint2*)(XC + base0 + (unsigned)s1i * 16384u + j * 16);
    }
    lds_barrier();

    auto body = [&](int t, uint2 (&xc)[2]) {
        const int st = dir ? (511 - t) : t;
        const int sld = dir ? (st - 2 < 0 ? 0 : st - 2)
                            : (st + 2 > 511 ? 511 : st + 2);
        const int p = t & 1;

        f32x4 acc[2], acc2[2];
#pragma unroll
        for (int j = 0; j < 2; ++j) {
            const unsigned d0 = xc[j].x, d1 = xc[j].y;
            acc[j][0] = biasv[j][0]; acc[j][1] = biasv[j][1];
            acc[j][2] = biasv[j][2]; acc[j][3] = biasv[j][3];
            acc2[j][0] = __uint_as_float(d0 << 16);
            acc2[j][1] = __uint_as_float(d0 & 0xffff0000u);
            acc2[j][2] = __uint_as_float(d1 << 16);
            acc2[j][3] = __uint_as_float(d1 & 0xffff0000u);
        }

        // prefetch x(t+2)
#pragma unroll
        for (int j = 0; j < 2; ++j)
            xc[j] = *(const uint2*)(XC + base0 + (unsigned)sld * 16384u + j * 16);

        f16x8 ah[8];
#pragma unroll
        for (int ks = 0; ks < 8; ++ks)
            ah[ks] = *(const f16x8*)&cF[p][ridx[ks]];
        // two independent depth-4 chains per output frag
#pragma unroll
        for (int ks = 0; ks < 4; ++ks) {
            acc[0]  = __builtin_amdgcn_mfma_f32_16x16x32_f16(wf[0][ks],     ah[ks],     acc[0],  0, 0, 0);
            acc[1]  = __builtin_amdgcn_mfma_f32_16x16x32_f16(wf[1][ks],     ah[ks],     acc[1],  0, 0, 0);
            acc2[0] = __builtin_amdgcn_mfma_f32_16x16x32_f16(wf[0][ks + 4], ah[ks + 4], acc2[0], 0, 0, 0);
            acc2[1] = __builtin_amdgcn_mfma_f32_16x16x32_f16(wf[1][ks + 4], ah[ks + 4], acc2[1], 0, 0, 0);
        }

#pragma unroll
        for (int j = 0; j < 2; ++j) {
            float t0, t1, t2, t3;
            {
                float z0 = acc[j][0] + acc2[j][0];
                float z1 = acc[j][1] + acc2[j][1];
                float z2 = acc[j][2] + acc2[j][2];
                float z3 = acc[j][3] + acc2[j][3];
                // tanh(z) = 1 - 2/(exp2(z*2*log2e)+1); inf-safe without clamp
                float e0 = __builtin_amdgcn_exp2f(z0 * 2.8853900817779268f);
                float e1 = __builtin_amdgcn_exp2f(z1 * 2.8853900817779268f);
                float e2 = __builtin_amdgcn_exp2f(z2 * 2.8853900817779268f);
                float e3 = __builtin_amdgcn_exp2f(z3 * 2.8853900817779268f);
                t0 = fmaf(-2.f, __builtin_amdgcn_rcpf(e0 + 1.f), 1.f);
                t1 = fmaf(-2.f, __builtin_amdgcn_rcpf(e1 + 1.f), 1.f);
                t2 = fmaf(-2.f, __builtin_amdgcn_rcpf(e2 + 1.f), 1.f);
                t3 = fmaf(-2.f, __builtin_amdgcn_rcpf(e3 + 1.f), 1.f);
            }
            // f16 pack -> 8B LDS store (critical path: feeds next step)
            union { hf16x2 h; unsigned u; } h0, h1;
            h0.h = __builtin_amdgcn_cvt_pkrtz(t0, t1);
            h1.h = __builtin_amdgcn_cvt_pkrtz(t2, t3);
            uint2 hw; hw.x = h0.u; hw.y = h1.u;
            *(uint2*)&cF[p ^ 1][widx[j]] = hw;
            // bf16 pack -> 8B global store (background; drains off critical path)
            uint2 pkb;
            asm("v_cvt_pk_bf16_f32 %0, %1, %2" : "=v"(pkb.x) : "v"(t0), "v"(t1));
            asm("v_cvt_pk_bf16_f32 %0, %1, %2" : "=v"(pkb.y) : "v"(t2), "v"(t3));
            *(uint2*)(XC + base0 + (unsigned)st * 16384u + j * 16) = pkb;
        }
        lds_barrier();
    };

    for (int t = 0; t < kS; t += 2) {
        body(t, xa);
        body(t + 1, xb);
    }
}

// maxlayer GEMM: A staged from 3 sources (XCL | E | XCR), B = Wmax. K=832.
__global__ __launch_bounds__(256) void maxlayer_mfma_kernel(
    const unsigned short* __restrict__ XCL, const unsigned short* __restrict__ E,
    const unsigned short* __restrict__ XCR, const unsigned short* __restrict__ Wmax,
    float* __restrict__ part_max)
{
    __shared__ unsigned short As[128 * 40];
    __shared__ unsigned short Bs[128 * 40];
    __shared__ float red[2][128];
    const int tid = threadIdx.x;
    const int mt = blockIdx.x, sc = blockIdx.y, b = blockIdx.z;
    const int col0 = mt * 128;
    const int lane = tid & 63;
    const int wave = tid >> 6;
    const int wrow = wave >> 1;
    const int wr = wrow * 64, wc = (wave & 1) * 64;
    const int l15 = lane & 15, lk = (lane >> 4) * 8;
    const int srow = tid >> 1;
    const int sh = (tid & 1) * 16;

    const int s = sc * 128 + srow;
    const unsigned short* baseL = XCL + ((size_t)s * 64 + b) * 256 + sh;
    const unsigned short* baseE = E + (size_t)(b * 512 + s) * 320 + sh;
    const unsigned short* baseR = XCR + ((size_t)s * 64 + b) * 256 + sh;
    const unsigned short* Bg = Wmax + (size_t)(col0 + srow) * 832 + sh;

    auto aptr = [&](int kk) -> const unsigned short* {
        if (kk < 8)  return baseL + kk * 32;
        if (kk < 18) return baseE + (kk - 8) * 32;
        return baseR + (kk - 18) * 32;
    };

    f32x4 acc[4][4] = {};
    float4 av0 = *(const float4*)aptr(0);
    float4 av1 = *(const float4*)(aptr(0) + 8);
    float4 bv0 = *(const float4*)Bg;
    float4 bv1 = *(const float4*)(Bg + 8);

    for (int kk = 0; kk < 26; ++kk) {
        __syncthreads();
        *(float4*)&As[srow * 40 + sh] = av0;
        *(float4*)&As[srow * 40 + sh + 8] = av1;
        *(float4*)&Bs[srow * 40 + sh] = bv0;
        *(float4*)&Bs[srow * 40 + sh + 8] = bv1;
        __syncthreads();
        if (kk < 25) {
            const unsigned short* ap = aptr(kk + 1);
            av0 = *(const float4*)ap;
            av1 = *(const float4*)(ap + 8);
            bv0 = *(const float4*)(Bg + (kk + 1) * 32);
            bv1 = *(const float4*)(Bg + (kk + 1) * 32 + 8);
        }
        s16x8 af[4], bf[4];
#pragma unroll
        for (int f = 0; f < 4; ++f) {
            af[f] = *(const s16x8*)&As[(wr + f * 16 + l15) * 40 + lk];
            bf[f] = *(const s16x8*)&Bs[(wc + f * 16 + l15) * 40 + lk];
        }
#pragma unroll
        for (int i = 0; i < 4; ++i)
#pragma unroll
            for (int j = 0; j < 4; ++j)
                acc[i][j] = __builtin_amdgcn_mfma_f32_16x16x32_bf16(af[i], bf[j], acc[i][j], 0, 0, 0);
    }

#pragma unroll
    for (int j = 0; j < 4; ++j) {
        float m = -1e30f;
#pragma unroll
        for (int i = 0; i < 4; ++i)
#pragma unroll
            for (int r = 0; r < 4; ++r) m = fmaxf(m, acc[i][j][r]);
        m = fmaxf(m, __shfl_xor(m, 16));
        m = fmaxf(m, __shfl_xor(m, 32));
        if (lane < 16) red[wrow][wc + j * 16 + lane] = m;
    }
    __syncthreads();
    if (tid < 128) {
        float v = fmaxf(red[0][tid], red[1][tid]);
        part_max[((size_t)(b * 4 + sc)) * kM + col0 + tid] = v;
    }
}

// final: combine partial maxes, tanh(.+max_b), doc layer, log_softmax.
__global__ __launch_bounds__(256) void final_kernel(
    const float* __restrict__ part_max, const float* __restrict__ max_b,
    const float* __restrict__ doc_w, const float* __restrict__ doc_b,
    float* __restrict__ out)
{
    const int b = blockIdx.x;
    const int t = threadIdx.x;
    __shared__ float ym[kM];
    __shared__ float red[160];
    __shared__ float logits[kC];

    for (int m = t; m < kM; m += 256) {
        float v = -1e30f;
        for (int ch = 0; ch < 4; ++ch)
            v = fmaxf(v, part_max[((size_t)(b * 4 + ch)) * kM + m]);
        ym[m] = fast_tanh(v + max_b[m]);
    }
    __syncthreads();
    if (t < 160) {
        int c = t >> 3, kg = t & 7;
        float s = 0.f;
        const float* wr = doc_w + c * kM + kg * 64;
        const float* yr = ym + kg * 64;
        for (int k = 0; k < 64; ++k) s += yr[k] * wr[k];
        red[t] = s;
    }
    __syncthreads();
    if (t < kC) {
        float s = doc_b[t];
        for (int kg = 0; kg < 8; ++kg) s += red[t * 8 + kg];
        logits[t] = s;
    }
    __syncthreads();
    if (t == 0) {
        float mx = logits[0];
        for (int c = 1; c < kC; ++c) mx = fmaxf(mx, logits[c]);
        float se = 0.f;
        for (int c = 0; c < kC; ++c) se += __expf(logits[c] - mx);
        float lse = mx + __logf(se);
        for (int c = 0; c < kC; ++c) out[b * kC + c] = logits[c] - lse;
    }
}

extern "C" void kernel_launch(void* const* d_in, const int* in_sizes, int n_in,
                              void* d_out, int out_size, void* d_ws, size_t ws_size,
                              hipStream_t stream) {
    const int* inp = (const int*)d_in[0];
    const float* emb_table = (const float*)d_in[1];
    const float* c_l0 = (const float*)d_in[2];
    const float* c_r0 = (const float*)d_in[3];
    const float* W_l_w = (const float*)d_in[4];
    const float* W_l_b = (const float*)d_in[5];
    const float* W_r_w = (const float*)d_in[6];
    const float* W_r_b = (const float*)d_in[7];
    const float* W_sl_w = (const float*)d_in[8];
    const float* W_sl_b = (const float*)d_in[9];
    const float* W_sr_w = (const float*)d_in[10];
    const float* W_sr_b = (const float*)d_in[11];
    const float* max_w = (const float*)d_in[12];
    const float* max_b = (const float*)d_in[13];
    const float* doc_w = (const float*)d_in[14];
    const float* doc_b = (const float*)d_in[15];
    float* out = (float*)d_out;

    // Workspace: 56,492,032 bytes total.
    char* w = (char*)d_ws;
    unsigned short* E     = (unsigned short*)(w);                 // 32768*320*2 = 20,971,520
    unsigned short* XCL   = (unsigned short*)(w + 20971520);      // 512*64*256*2 = 16,777,216
    unsigned short* XCR   = (unsigned short*)(w + 37748736);      // 16,777,216
    unsigned short* Wmax  = (unsigned short*)(w + 54525952);      // 851,968
    unsigned short* Wproj = (unsigned short*)(w + 55377920);      // 327,680
    float* part_max       = (float*)(w + 55705600);               // 524,288
    unsigned short* Wscan = (unsigned short*)(w + 56229888);      // 262,144

    prepw_kernel<<<(512 * 832 + 255) / 256, 256, 0, stream>>>(
        max_w, W_sl_w, W_sr_w, W_l_w, W_r_w, Wmax, Wproj, Wscan);
    gather_kernel<<<kS * kB, 128, 0, stream>>>(inp, emb_table, E);
    proj_mfma_kernel<<<dim3(256, 4), 256, 0, stream>>>(
        E, Wproj, W_sl_b, W_sr_b, XCL, XCR);
    scan_mfma_kernel<<<8, 512, 0, stream>>>(
        c_l0, c_r0, W_l_b, W_r_b, Wscan, XCL, XCR);
    maxlayer_mfma_kernel<<<dim3(4, 4, 64), 256, 0, stream>>>(
        XCL, E, XCR, Wmax, part_max);
    final_kernel<<<kB, 256, 0, stream>>>(part_max, max_b, doc_w, doc_b, out);
}

// Round 11
// 518.467 us; speedup vs baseline: 1.0020x; 1.0020x over previous
//
#include <hip/hip_runtime.h>
#include <hip/hip_bf16.h>

// Problem dims
constexpr int kS = 512;
constexpr int kB = 64;
constexpr int kE = 300;
constexpr int kH = 256;
constexpr int kM = 512;
constexpr int kC = 20;

typedef short s16x8 __attribute__((ext_vector_type(8)));
typedef float f32x4 __attribute__((ext_vector_type(4)));
typedef unsigned short u16x4 __attribute__((ext_vector_type(4)));
typedef _Float16 f16x8 __attribute__((ext_vector_type(8)));
typedef __fp16 hf16x2 __attribute__((ext_vector_type(2)));

__device__ __forceinline__ float fast_tanh(float z) {
    z = fminf(15.f, fmaxf(-15.f, z));
    float e = __expf(2.f * z);
    return 1.f - 2.f / (e + 1.f);
}

__device__ __forceinline__ unsigned short f2bf(float f) {
    __hip_bfloat16 h = __float2bfloat16(f);
    return *(unsigned short*)&h;
}
union F16U { _Float16 h; unsigned short u; };
__device__ __forceinline__ unsigned short f16bits(_Float16 h) { F16U x; x.h = h; return x.u; }

// LDS-only barrier: waits ds ops, NOT global ops (no vmcnt drain).
__device__ __forceinline__ void lds_barrier() {
    asm volatile("s_waitcnt lgkmcnt(0)\n\ts_barrier" ::: "memory");
}

// ---------------------------------------------------------------------------
// Buffers:
//   E   [32768][320] bf16 : emb (300) + zero pad (20); row = b*512+s
//   XCL [512][64][256] bf16: proj pre-acts -> scan overwrites with c_ls (in place)
//   XCR [512][64][256] bf16: same for right scan
//   Wmax [512][832] bf16 (re-ordered cols to match XCL|E|XCR concat)
//   Wproj [512][320] bf16, Wscan [2][256][256] f16
// ---------------------------------------------------------------------------

__global__ __launch_bounds__(256) void prepw_kernel(
    const float* __restrict__ max_w,
    const float* __restrict__ wsl, const float* __restrict__ wsr,
    const float* __restrict__ wl, const float* __restrict__ wr,
    unsigned short* __restrict__ Wmax, unsigned short* __restrict__ Wproj,
    unsigned short* __restrict__ Wscan)
{
    int idx = blockIdx.x * 256 + threadIdx.x;
    if (idx < 512 * 832) {
        int r = idx / 832, c = idx - r * 832;
        float v;
        if (c < 556)      v = max_w[r * 812 + c];
        else if (c < 576) v = 0.f;
        else              v = max_w[r * 812 + (c - 20)];
        Wmax[idx] = f2bf(v);
    }
    if (idx < 512 * 320) {
        int r = idx / 320, c = idx - r * 320;
        float v = 0.f;
        if (c < 300) v = (r < 256) ? wsl[r * 300 + c] : wsr[(r - 256) * 300 + c];
        Wproj[idx] = f2bf(v);
    }
    if (idx < 2 * 256 * 256) {
        int d = idx >> 16, rc = idx & 65535;
        float v = (d ? wr : wl)[rc];
        Wscan[idx] = f16bits((_Float16)v);
    }
}

// gather: emb rows -> E[b*512+s][0..300), zeros [300,320)
__global__ __launch_bounds__(128) void gather_kernel(
    const int* __restrict__ inp, const float* __restrict__ emb_table,
    unsigned short* __restrict__ E)
{
    const int row = blockIdx.x;          // b*512 + s
    const int b = row >> 9, s = row & 511;
    const int t = threadIdx.x;
    unsigned short* dst = E + (size_t)row * 320;
    const int v = inp[s * kB + b];
    const float* src = emb_table + (size_t)v * kE;
    if (t < 75) {
        float4 f = *(const float4*)&src[t * 4];
        u16x4 o = { f2bf(f.x), f2bf(f.y), f2bf(f.z), f2bf(f.w) };
        *(u16x4*)&dst[t * 4] = o;
    } else if (t < 80) {
        u16x4 z = { 0, 0, 0, 0 };
        *(u16x4*)&dst[300 + (t - 75) * 4] = z;
    }
}

// proj GEMM: A = E (K=320), B = Wproj. Epilogue -> XCL/XCR [s][b][256] bf16.
__global__ __launch_bounds__(256) void proj_mfma_kernel(
    const unsigned short* __restrict__ E,
    const unsigned short* __restrict__ Wproj,
    const float* __restrict__ b_sl, const float* __restrict__ b_sr,
    unsigned short* __restrict__ XCL, unsigned short* __restrict__ XCR)
{
    __shared__ unsigned short As[128 * 40];
    __shared__ unsigned short Bs[128 * 40];
    const int tid = threadIdx.x;
    const int row0 = blockIdx.x * 128;
    const int col0 = blockIdx.y * 128;
    const int lane = tid & 63;
    const int wave = tid >> 6;
    const int wr = (wave >> 1) * 64, wc = (wave & 1) * 64;
    const int l15 = lane & 15, lk = (lane >> 4) * 8;
    const int srow = tid >> 1;
    const int sh = (tid & 1) * 16;

    const unsigned short* Ag = E + (size_t)(row0 + srow) * 320 + sh;
    const unsigned short* Bg = Wproj + (size_t)(col0 + srow) * 320 + sh;

    f32x4 acc[4][4] = {};
    float4 av0 = *(const float4*)Ag;
    float4 av1 = *(const float4*)(Ag + 8);
    float4 bv0 = *(const float4*)Bg;
    float4 bv1 = *(const float4*)(Bg + 8);

    for (int kk = 0; kk < 10; ++kk) {
        __syncthreads();
        *(float4*)&As[srow * 40 + sh] = av0;
        *(float4*)&As[srow * 40 + sh + 8] = av1;
        *(float4*)&Bs[srow * 40 + sh] = bv0;
        *(float4*)&Bs[srow * 40 + sh + 8] = bv1;
        __syncthreads();
        if (kk < 9) {
            av0 = *(const float4*)(Ag + (kk + 1) * 32);
            av1 = *(const float4*)(Ag + (kk + 1) * 32 + 8);
            bv0 = *(const float4*)(Bg + (kk + 1) * 32);
            bv1 = *(const float4*)(Bg + (kk + 1) * 32 + 8);
        }
        s16x8 af[4], bf[4];
#pragma unroll
        for (int f = 0; f < 4; ++f) {
            af[f] = *(const s16x8*)&As[(wr + f * 16 + l15) * 40 + lk];
            bf[f] = *(const s16x8*)&Bs[(wc + f * 16 + l15) * 40 + lk];
        }
#pragma unroll
        for (int i = 0; i < 4; ++i)
#pragma unroll
            for (int j = 0; j < 4; ++j)
                acc[i][j] = __builtin_amdgcn_mfma_f32_16x16x32_bf16(af[i], bf[j], acc[i][j], 0, 0, 0);
    }

    const int rbase = row0 + wr + (lane >> 4) * 4;
#pragma unroll
    for (int j = 0; j < 4; ++j) {
        const int col = col0 + wc + j * 16 + l15;           // h' in [0,512)
        const float bias = (col < kH) ? b_sl[col] : b_sr[col - kH];
        unsigned short* X = (col < kH) ? XCL : XCR;
        const int ccol = col & 255;
#pragma unroll
        for (int i = 0; i < 4; ++i) {
#pragma unroll
            for (int r = 0; r < 4; ++r) {
                const int row = rbase + i * 16 + r;         // b*512+s
                const int s = row & 511, b = row >> 9;
                X[((size_t)s * 64 + b) * 256 + ccol] = f2bf(acc[i][j][r] + bias);
            }
        }
    }
}

// ---------------------------------------------------------------------------
// MFMA scan, swapped operands (A=W, B=c). 8 blocks = 2 dir x 4 bgroups of 16.
// 512 threads (8 waves); wave owns 32 output cols. W fragments PINNED in
// VGPRs via asm tie (R10 post-mortem: VGPR_Count=64 proved the allocator
// sank the wf loads into the step loop -> 16 L2 reloads/step on the critical
// path). Single-f16 recurrence in swizzled double-buffered LDS; 1 LDS-only
// barrier per step.
// ---------------------------------------------------------------------------
__global__ __launch_bounds__(512, 2) void scan_mfma_kernel(
    const float* __restrict__ c_l0, const float* __restrict__ c_r0,
    const float* __restrict__ b_l, const float* __restrict__ b_r,
    const unsigned short* __restrict__ Wscan,   // [2][256][256] f16
    unsigned short* __restrict__ XCL, unsigned short* __restrict__ XCR)
{
    __shared__ unsigned short cF[2][16 * 256];

    const int dir = blockIdx.x >> 2;
    const int bg  = blockIdx.x & 3;
    const int tid = threadIdx.x;
    const int lane = tid & 63;
    const int wave = tid >> 6;          // 0..7
    const int l15 = lane & 15;          // batch-in-group; cF row
    const int q4  = lane >> 4;          // k-slice for frags; col-subtile out
    const int n0  = wave * 32;

    const float* bias = dir ? b_r : b_l;
    const float* c0v  = dir ? c_r0 : c_l0;
    const unsigned short* W = Wscan + (dir << 16);
    unsigned short* XC = dir ? XCR : XCL;

    // A-frags (W): rows n0+j*16+l15 (output cols), k = ks*32 + q4*8
    f16x8 wf[2][8];
#pragma unroll
    for (int j = 0; j < 2; ++j)
#pragma unroll
        for (int ks = 0; ks < 8; ++ks)
            wf[j][ks] = *(const f16x8*)&W[(n0 + j * 16 + l15) * 256 + ks * 32 + q4 * 8];
    // Pin in VGPRs: value becomes asm-defined -> cannot be re-materialized by
    // reloading from Wscan inside the loop; must stay register-resident.
#pragma unroll
    for (int j = 0; j < 2; ++j)
#pragma unroll
        for (int ks = 0; ks < 8; ++ks)
            asm volatile("" : "+v"(wf[j][ks]));

    // biases for this thread's 8 output cols
    float biasv[2][4];
#pragma unroll
    for (int j = 0; j < 2; ++j)
#pragma unroll
        for (int r = 0; r < 4; ++r)
            biasv[j][r] = bias[n0 + j * 16 + q4 * 4 + r];

    // global slot (shorts): batch (bg*16+l15), cols n0+q4*4 (+j*16 imm)
    const unsigned int base0 = (unsigned)((bg * 16 + l15) * 256 + n0 + q4 * 4);

    // swizzled LDS offsets (row = l15 for both read and write)
    int ridx[8], widx[2];
#pragma unroll
    for (int ks = 0; ks < 8; ++ks)
        ridx[ks] = (l15 * 256 + ks * 32 + q4 * 8) ^ ((l15 & 7) << 3);
#pragma unroll
    for (int j = 0; j < 2; ++j)
        widx[j] = (l15 * 256 + n0 + j * 16 + q4 * 4) ^ ((l15 & 7) << 3);

    // init c0 into cF[0] (all 16 batch rows share c0)
    if (tid < 256) {
        unsigned short hb = f16bits((_Float16)c0v[tid]);
        for (int row = 0; row < 16; ++row)
            cF[0][(row * 256 + tid) ^ ((row & 7) << 3)] = hb;
    }

    // prologue x loads: steps 0,1
    const int s0i = dir ? 511 : 0;
    const int s1i = dir ? 510 : 1;
    uint2 xa[2], xb[2];
#pragma unroll
    for (int j = 0; j < 2; ++j) {
        xa[j] = *(const uint2*)(XC + base0 + (unsigned)s0i * 16384u + j * 16);
        xb[j] = *(const uint2*)(XC + base0 + (unsigned)s1i * 16384u + j * 16);
    }
    lds_barrier();

    auto body = [&](int t, uint2 (&xc)[2]) {
        const int st = dir ? (511 - t) : t;
        const int sld = dir ? (st - 2 < 0 ? 0 : st - 2)
                            : (st + 2 > 511 ? 511 : st + 2);
        const int p = t & 1;

        f32x4 acc[2], acc2[2];
#pragma unroll
        for (int j = 0; j < 2; ++j) {
            const unsigned d0 = xc[j].x, d1 = xc[j].y;
            acc[j][0] = biasv[j][0]; acc[j][1] = biasv[j][1];
            acc[j][2] = biasv[j][2]; acc[j][3] = biasv[j][3];
            acc2[j][0] = __uint_as_float(d0 << 16);
            acc2[j][1] = __uint_as_float(d0 & 0xffff0000u);
            acc2[j][2] = __uint_as_float(d1 << 16);
            acc2[j][3] = __uint_as_float(d1 & 0xffff0000u);
        }

        // prefetch x(t+2)
#pragma unroll
        for (int j = 0; j < 2; ++j)
            xc[j] = *(const uint2*)(XC + base0 + (unsigned)sld * 16384u + j * 16);

        f16x8 ah[8];
#pragma unroll
        for (int ks = 0; ks < 8; ++ks)
            ah[ks] = *(const f16x8*)&cF[p][ridx[ks]];
        // two independent depth-4 chains per output frag
#pragma unroll
        for (int ks = 0; ks < 4; ++ks) {
            acc[0]  = __builtin_amdgcn_mfma_f32_16x16x32_f16(wf[0][ks],     ah[ks],     acc[0],  0, 0, 0);
            acc[1]  = __builtin_amdgcn_mfma_f32_16x16x32_f16(wf[1][ks],     ah[ks],     acc[1],  0, 0, 0);
            acc2[0] = __builtin_amdgcn_mfma_f32_16x16x32_f16(wf[0][ks + 4], ah[ks + 4], acc2[0], 0, 0, 0);
            acc2[1] = __builtin_amdgcn_mfma_f32_16x16x32_f16(wf[1][ks + 4], ah[ks + 4], acc2[1], 0, 0, 0);
        }

#pragma unroll
        for (int j = 0; j < 2; ++j) {
            float t0, t1, t2, t3;
            {
                float z0 = acc[j][0] + acc2[j][0];
                float z1 = acc[j][1] + acc2[j][1];
                float z2 = acc[j][2] + acc2[j][2];
                float z3 = acc[j][3] + acc2[j][3];
                // tanh(z) = 1 - 2/(exp2(z*2*log2e)+1); inf-safe without clamp
                float e0 = __builtin_amdgcn_exp2f(z0 * 2.8853900817779268f);
                float e1 = __builtin_amdgcn_exp2f(z1 * 2.8853900817779268f);
                float e2 = __builtin_amdgcn_exp2f(z2 * 2.8853900817779268f);
                float e3 = __builtin_amdgcn_exp2f(z3 * 2.8853900817779268f);
                t0 = fmaf(-2.f, __builtin_amdgcn_rcpf(e0 + 1.f), 1.f);
                t1 = fmaf(-2.f, __builtin_amdgcn_rcpf(e1 + 1.f), 1.f);
                t2 = fmaf(-2.f, __builtin_amdgcn_rcpf(e2 + 1.f), 1.f);
                t3 = fmaf(-2.f, __builtin_amdgcn_rcpf(e3 + 1.f), 1.f);
            }
            // f16 pack -> 8B LDS store (critical path: feeds next step)
            union { hf16x2 h; unsigned u; } h0, h1;
            h0.h = __builtin_amdgcn_cvt_pkrtz(t0, t1);
            h1.h = __builtin_amdgcn_cvt_pkrtz(t2, t3);
            uint2 hw; hw.x = h0.u; hw.y = h1.u;
            *(uint2*)&cF[p ^ 1][widx[j]] = hw;
            // bf16 pack -> 8B global store (background; drains off critical path)
            uint2 pkb;
            asm("v_cvt_pk_bf16_f32 %0, %1, %2" : "=v"(pkb.x) : "v"(t0), "v"(t1));
            asm("v_cvt_pk_bf16_f32 %0, %1, %2" : "=v"(pkb.y) : "v"(t2), "v"(t3));
            *(uint2*)(XC + base0 + (unsigned)st * 16384u + j * 16) = pkb;
        }
        lds_barrier();
    };

    for (int t = 0; t < kS; t += 2) {
        body(t, xa);
        body(t + 1, xb);
    }
}

// maxlayer GEMM: A staged from 3 sources (XCL | E | XCR), B = Wmax. K=832.
__global__ __launch_bounds__(256) void maxlayer_mfma_kernel(
    const unsigned short* __restrict__ XCL, const unsigned short* __restrict__ E,
    const unsigned short* __restrict__ XCR, const unsigned short* __restrict__ Wmax,
    float* __restrict__ part_max)
{
    __shared__ unsigned short As[128 * 40];
    __shared__ unsigned short Bs[128 * 40];
    __shared__ float red[2][128];
    const int tid = threadIdx.x;
    const int mt = blockIdx.x, sc = blockIdx.y, b = blockIdx.z;
    const int col0 = mt * 128;
    const int lane = tid & 63;
    const int wave = tid >> 6;
    const int wrow = wave >> 1;
    const int wr = wrow * 64, wc = (wave & 1) * 64;
    const int l15 = lane & 15, lk = (lane >> 4) * 8;
    const int srow = tid >> 1;
    const int sh = (tid & 1) * 16;

    const int s = sc * 128 + srow;
    const unsigned short* baseL = XCL + ((size_t)s * 64 + b) * 256 + sh;
    const unsigned short* baseE = E + (size_t)(b * 512 + s) * 320 + sh;
    const unsigned short* baseR = XCR + ((size_t)s * 64 + b) * 256 + sh;
    const unsigned short* Bg = Wmax + (size_t)(col0 + srow) * 832 + sh;

    auto aptr = [&](int kk) -> const unsigned short* {
        if (kk < 8)  return baseL + kk * 32;
        if (kk < 18) return baseE + (kk - 8) * 32;
        return baseR + (kk - 18) * 32;
    };

    f32x4 acc[4][4] = {};
    float4 av0 = *(const float4*)aptr(0);
    float4 av1 = *(const float4*)(aptr(0) + 8);
    float4 bv0 = *(const float4*)Bg;
    float4 bv1 = *(const float4*)(Bg + 8);

    for (int kk = 0; kk < 26; ++kk) {
        __syncthreads();
        *(float4*)&As[srow * 40 + sh] = av0;
        *(float4*)&As[srow * 40 + sh + 8] = av1;
        *(float4*)&Bs[srow * 40 + sh] = bv0;
        *(float4*)&Bs[srow * 40 + sh + 8] = bv1;
        __syncthreads();
        if (kk < 25) {
            const unsigned short* ap = aptr(kk + 1);
            av0 = *(const float4*)ap;
            av1 = *(const float4*)(ap + 8);
            bv0 = *(const float4*)(Bg + (kk + 1) * 32);
            bv1 = *(const float4*)(Bg + (kk + 1) * 32 + 8);
        }
        s16x8 af[4], bf[4];
#pragma unroll
        for (int f = 0; f < 4; ++f) {
            af[f] = *(const s16x8*)&As[(wr + f * 16 + l15) * 40 + lk];
            bf[f] = *(const s16x8*)&Bs[(wc + f * 16 + l15) * 40 + lk];
        }
#pragma unroll
        for (int i = 0; i < 4; ++i)
#pragma unroll
            for (int j = 0; j < 4; ++j)
                acc[i][j] = __builtin_amdgcn_mfma_f32_16x16x32_bf16(af[i], bf[j], acc[i][j], 0, 0, 0);
    }

#pragma unroll
    for (int j = 0; j < 4; ++j) {
        float m = -1e30f;
#pragma unroll
        for (int i = 0; i < 4; ++i)
#pragma unroll
            for (int r = 0; r < 4; ++r) m = fmaxf(m, acc[i][j][r]);
        m = fmaxf(m, __shfl_xor(m, 16));
        m = fmaxf(m, __shfl_xor(m, 32));
        if (lane < 16) red[wrow][wc + j * 16 + lane] = m;
    }
    __syncthreads();
    if (tid < 128) {
        float v = fmaxf(red[0][tid], red[1][tid]);
        part_max[((size_t)(b * 4 + sc)) * kM + col0 + tid] = v;
    }
}

// final: combine partial maxes, tanh(.+max_b), doc layer, log_softmax.
__global__ __launch_bounds__(256) void final_kernel(
    const float* __restrict__ part_max, const float* __restrict__ max_b,
    const float* __restrict__ doc_w, const float* __restrict__ doc_b,
    float* __restrict__ out)
{
    const int b = blockIdx.x;
    const int t = threadIdx.x;
    __shared__ float ym[kM];
    __shared__ float red[160];
    __shared__ float logits[kC];

    for (int m = t; m < kM; m += 256) {
        float v = -1e30f;
        for (int ch = 0; ch < 4; ++ch)
            v = fmaxf(v, part_max[((size_t)(b * 4 + ch)) * kM + m]);
        ym[m] = fast_tanh(v + max_b[m]);
    }
    __syncthreads();
    if (t < 160) {
        int c = t >> 3, kg = t & 7;
        float s = 0.f;
        const float* wr = doc_w + c * kM + kg * 64;
        const float* yr = ym + kg * 64;
        for (int k = 0; k < 64; ++k) s += yr[k] * wr[k];
        red[t] = s;
    }
    __syncthreads();
    if (t < kC) {
        float s = doc_b[t];
        for (int kg = 0; kg < 8; ++kg) s += red[t * 8 + kg];
        logits[t] = s;
    }
    __syncthreads();
    if (t == 0) {
        float mx = logits[0];
        for (int c = 1; c < kC; ++c) mx = fmaxf(mx, logits[c]);
        float se = 0.f;
        for (int c = 0; c < kC; ++c) se += __expf(logits[c] - mx);
        float lse = mx + __logf(se);
        for (int c = 0; c < kC; ++c) out[b * kC + c] = logits[c] - lse;
    }
}

extern "C" void kernel_launch(void* const* d_in, const int* in_sizes, int n_in,
                              void* d_out, int out_size, void* d_ws, size_t ws_size,
                              hipStream_t stream) {
    const int* inp = (const int*)d_in[0];
    const float* emb_table = (const float*)d_in[1];
    const float* c_l0 = (const float*)d_in[2];
    const float* c_r0 = (const float*)d_in[3];
    const float* W_l_w = (const float*)d_in[4];
    const float* W_l_b = (const float*)d_in[5];
    const float* W_r_w = (const float*)d_in[6];
    const float* W_r_b = (const float*)d_in[7];
    const float* W_sl_w = (const float*)d_in[8];
    const float* W_sl_b = (const float*)d_in[9];
    const float* W_sr_w = (const float*)d_in[10];
    const float* W_sr_b = (const float*)d_in[11];
    const float* max_w = (const float*)d_in[12];
    const float* max_b = (const float*)d_in[13];
    const float* doc_w = (const float*)d_in[14];
    const float* doc_b = (const float*)d_in[15];
    float* out = (float*)d_out;

    // Workspace: 56,492,032 bytes total.
    char* w = (char*)d_ws;
    unsigned short* E     = (unsigned short*)(w);                 // 32768*320*2 = 20,971,520
    unsigned short* XCL   = (unsigned short*)(w + 20971520);      // 512*64*256*2 = 16,777,216
    unsigned short* XCR   = (unsigned short*)(w + 37748736);      // 16,777,216
    unsigned short* Wmax  = (unsigned short*)(w + 54525952);      // 851,968
    unsigned short* Wproj = (unsigned short*)(w + 55377920);      // 327,680
    float* part_max       = (float*)(w + 55705600);               // 524,288
    unsigned short* Wscan = (unsigned short*)(w + 56229888);      // 262,144

    prepw_kernel<<<(512 * 832 + 255) / 256, 256, 0, stream>>>(
        max_w, W_sl_w, W_sr_w, W_l_w, W_r_w, Wmax, Wproj, Wscan);
    gather_kernel<<<kS * kB, 128, 0, stream>>>(inp, emb_table, E);
    proj_mfma_kernel<<<dim3(256, 4), 256, 0, stream>>>(
        E, Wproj, W_sl_b, W_sr_b, XCL, XCR);
    scan_mfma_kernel<<<8, 512, 0, stream>>>(
        c_l0, c_r0, W_l_b, W_r_b, Wscan, XCL, XCR);
    maxlayer_mfma_kernel<<<dim3(4, 4, 64), 256, 0, stream>>>(
        XCL, E, XCR, Wmax, part_max);
    final_kernel<<<kB, 256, 0, stream>>>(part_max, max_b, doc_w, doc_b, out);
}